// Round 4
// baseline (697.391 us; speedup 1.0000x reference)
//
#include <hip/hip_runtime.h>

#define N_NODES 100000
#define N_EDGES 1600000
#define F 64
#define NPB 256                              // nodes per bucket (dst>>8)
#define NB ((N_NODES + NPB - 1) / NPB)       // 391 buckets
#define CAP 4608                             // bucket capacity (mean 4096, +8 sigma)

typedef unsigned short ushort_t;
typedef unsigned int uint_t;

// round-to-nearest-even float -> bf16 bits
__device__ __forceinline__ ushort_t f2bf(float x) {
    uint_t u = __float_as_uint(x);
    u += 0x7FFFu + ((u >> 16) & 1u);
    return (ushort_t)(u >> 16);
}
__device__ __forceinline__ float bf2f(ushort_t b) {
    return __uint_as_float(((uint_t)b) << 16);
}

// ---------------------------------------------------------------------------
// Kernel 1: hn[r][c] = bf16( (sum_k h[r][k] * W[k][c]) * norm[r] )
// ---------------------------------------------------------------------------
__global__ void gemm_norm_kernel(const float* __restrict__ h,
                                 const float* __restrict__ w,
                                 const float* __restrict__ norm,
                                 ushort_t* __restrict__ hn) {
    __shared__ float w_lds[F][F];
    __shared__ float h_lds[4][F];

    for (int i = threadIdx.x; i < F * F; i += blockDim.x)
        w_lds[i / F][i % F] = w[i];
    __syncthreads();

    const int rl = threadIdx.x >> 6;
    const int c  = threadIdx.x & 63;

    for (int r0 = blockIdx.x * 4; r0 < N_NODES; r0 += gridDim.x * 4) {
        const int r = r0 + rl;
        h_lds[rl][c] = (r < N_NODES) ? h[(size_t)r * F + c] : 0.f;
        __syncthreads();
        if (r < N_NODES) {
            float acc = 0.f;
#pragma unroll
            for (int k = 0; k < F; ++k)
                acc += h_lds[rl][k] * w_lds[k][c];
            hn[(size_t)r * F + c] = f2bf(acc * norm[r]);
        }
        __syncthreads();
    }
}

// ---------------------------------------------------------------------------
// split: bucket-append packed (src<<8 | dst&255) records. Appends advance a
// per-bucket tail monotonically -> stores cluster on ~2 hot lines per bucket.
// ---------------------------------------------------------------------------
__global__ void split_kernel(const int* __restrict__ src,
                             const int* __restrict__ dst,
                             int* __restrict__ bcnt,
                             uint_t* __restrict__ bpack) {
    const int i = blockIdx.x * blockDim.x + threadIdx.x;
    if (i >= N_EDGES) return;
    const int d = dst[i];
    const int b = d >> 8;
    const int pos = atomicAdd(&bcnt[b], 1);
    if (pos < CAP)
        bpack[(size_t)b * CAP + pos] = ((uint_t)src[i] << 8) | (uint_t)(d & 255);
}

// ---------------------------------------------------------------------------
// bucket_scan: exclusive scan of 391 bucket counts (one block).
// ---------------------------------------------------------------------------
__global__ void bucket_scan_kernel(const int* __restrict__ bcnt,
                                   int* __restrict__ bbase,
                                   int* __restrict__ offsets) {
    __shared__ int lds[512];
    const int t = threadIdx.x;
    const int v = (t < NB) ? min(bcnt[t], CAP) : 0;
    lds[t] = v;
    __syncthreads();
    int acc = v;
#pragma unroll
    for (int off = 1; off < 512; off <<= 1) {
        const int add = (t >= off) ? lds[t - off] : 0;
        __syncthreads();
        acc += add;
        lds[t] = acc;
        __syncthreads();
    }
    if (t < NB) bbase[t] = acc - v;
    if (t == 511) offsets[N_NODES] = acc;   // total placed edges
}

// ---------------------------------------------------------------------------
// build: one block per bucket. LDS count -> LDS scan -> per-node offsets ->
// place esrc via LDS cursors. Each bucket's esrc window written by ONE block.
// ---------------------------------------------------------------------------
__launch_bounds__(256)
__global__ void build_kernel(const int* __restrict__ bcnt,
                             const int* __restrict__ bbase,
                             const uint_t* __restrict__ bpack,
                             int* __restrict__ offsets,
                             int* __restrict__ esrc) {
    __shared__ uint_t ebuf[CAP];   // 18.4 KB
    __shared__ int cnt[NPB];
    __shared__ int cur[NPB];

    const int b = blockIdx.x;
    const int t = threadIdx.x;
    const int n = min(bcnt[b], CAP);
    const int base = bbase[b];

    cnt[t] = 0;
    __syncthreads();

    for (int i = t; i < n; i += 256) {
        const uint_t v = bpack[(size_t)b * CAP + i];
        ebuf[i] = v;
        atomicAdd(&cnt[v & 255u], 1);
    }
    __syncthreads();

    // Hillis-Steele inclusive scan of cnt (cur as scratch)
    const int v = cnt[t];
    int acc = v;
    cur[t] = acc;
    __syncthreads();
#pragma unroll
    for (int off = 1; off < 256; off <<= 1) {
        const int add = (t >= off) ? cur[t - off] : 0;
        __syncthreads();
        acc += add;
        cur[t] = acc;
        __syncthreads();
    }
    const int excl = acc - v;

    const int node = b * NPB + t;
    if (node < N_NODES) offsets[node] = base + excl;
    cur[t] = base + excl;   // cursor for placement
    __syncthreads();

    for (int i = t; i < n; i += 256) {
        const uint_t e = ebuf[i];
        const int p = atomicAdd(&cur[e & 255u], 1);
        esrc[p] = (int)(e >> 8);
    }
}

// ---------------------------------------------------------------------------
// Gather-sum: one wave per dst node, lane = column (bf16 hn). Fused post-scale.
// ---------------------------------------------------------------------------
__global__ void gather_kernel(const ushort_t* __restrict__ hn,
                              const int* __restrict__ offsets,
                              const int* __restrict__ esrc,
                              const float* __restrict__ norm,
                              float* __restrict__ out) {
    const int node = blockIdx.x * (blockDim.x >> 6) + (threadIdx.x >> 6);
    const int lane = threadIdx.x & 63;
    if (node >= N_NODES) return;

    const int beg = offsets[node];
    const int end = offsets[node + 1];

    float acc = 0.f;
    int i = beg;
    for (; i + 3 < end; i += 4) {
        const int s0 = esrc[i], s1 = esrc[i + 1], s2 = esrc[i + 2], s3 = esrc[i + 3];
        const ushort_t a = hn[(size_t)s0 * F + lane];
        const ushort_t b = hn[(size_t)s1 * F + lane];
        const ushort_t c = hn[(size_t)s2 * F + lane];
        const ushort_t d = hn[(size_t)s3 * F + lane];
        acc += bf2f(a) + bf2f(b) + bf2f(c) + bf2f(d);
    }
    for (; i < end; ++i)
        acc += bf2f(hn[(size_t)esrc[i] * F + lane]);

    out[(size_t)node * F + lane] = acc * norm[node];
}

extern "C" void kernel_launch(void* const* d_in, const int* in_sizes, int n_in,
                              void* d_out, int out_size, void* d_ws, size_t ws_size,
                              hipStream_t stream) {
    const float* h    = (const float*)d_in[0];
    const float* w    = (const float*)d_in[1];
    const float* norm = (const float*)d_in[2];
    const int*   src  = (const int*)d_in[3];
    const int*   dst  = (const int*)d_in[4];
    float* out = (float*)d_out;

    // Workspace layout (256-aligned chunks), total ~26.8 MB:
    char* ws = (char*)d_ws;
    ushort_t* hn   = (ushort_t*)ws;                      // 12,800,000 B
    uint_t* bpack  = (uint_t*)(ws + 12800000);           //  7,206,912 B (NB*CAP*4)
    int* bcnt      = (int*)(ws + 20006912);              //      2,048 B
    int* bbase     = (int*)(ws + 20008960);              //      2,048 B
    int* offsets   = (int*)(ws + 20011008);              //    400,384 B
    int* esrc      = (int*)(ws + 20411392);              //  6,400,000 B

    hipMemsetAsync(bcnt, 0, NB * sizeof(int), stream);

    gemm_norm_kernel<<<2048, 256, 0, stream>>>(h, w, norm, hn);

    split_kernel<<<(N_EDGES + 255) / 256, 256, 0, stream>>>(src, dst, bcnt, bpack);
    bucket_scan_kernel<<<1, 512, 0, stream>>>(bcnt, bbase, offsets);
    build_kernel<<<NB, 256, 0, stream>>>(bcnt, bbase, bpack, offsets, esrc);

    gather_kernel<<<(N_NODES + 3) / 4, 256, 0, stream>>>(hn, offsets, esrc, norm, out);
}

// Round 5
// 157.881 us; speedup vs baseline: 4.4172x; 4.4172x over previous
//
#include <hip/hip_runtime.h>

#define N_NODES 100000
#define N_EDGES 1600000
#define F 64
#define NPB 256                              // nodes per bucket (dst>>8)
#define NB ((N_NODES + NPB - 1) / NPB)       // 391 buckets
#define CAP 4608                             // bucket capacity (mean 4096, +8 sigma)
#define BLK_E 4096                           // edges per split block
#define NSPLIT ((N_EDGES + BLK_E - 1) / BLK_E)   // 391

typedef unsigned short ushort_t;
typedef unsigned int uint_t;

// round-to-nearest-even float -> bf16 bits
__device__ __forceinline__ ushort_t f2bf(float x) {
    uint_t u = __float_as_uint(x);
    u += 0x7FFFu + ((u >> 16) & 1u);
    return (ushort_t)(u >> 16);
}
__device__ __forceinline__ float bf2f(ushort_t b) {
    return __uint_as_float(((uint_t)b) << 16);
}

// ---------------------------------------------------------------------------
// Kernel 1: hn[r][c] = bf16( (sum_k h[r][k] * W[k][c]) * norm[r] )
// ---------------------------------------------------------------------------
__global__ void gemm_norm_kernel(const float* __restrict__ h,
                                 const float* __restrict__ w,
                                 const float* __restrict__ norm,
                                 ushort_t* __restrict__ hn) {
    __shared__ float w_lds[F][F];
    __shared__ float h_lds[4][F];

    for (int i = threadIdx.x; i < F * F; i += blockDim.x)
        w_lds[i / F][i % F] = w[i];
    __syncthreads();

    const int rl = threadIdx.x >> 6;
    const int c  = threadIdx.x & 63;

    for (int r0 = blockIdx.x * 4; r0 < N_NODES; r0 += gridDim.x * 4) {
        const int r = r0 + rl;
        h_lds[rl][c] = (r < N_NODES) ? h[(size_t)r * F + c] : 0.f;
        __syncthreads();
        if (r < N_NODES) {
            float acc = 0.f;
#pragma unroll
            for (int k = 0; k < F; ++k)
                acc += h_lds[rl][k] * w_lds[k][c];
            hn[(size_t)r * F + c] = f2bf(acc * norm[r]);
        }
        __syncthreads();
    }
}

// ---------------------------------------------------------------------------
// split: LDS-privatized histogram + bulk reserve + LDS-cursor placement.
// Each block owns a contiguous 4096-edge chunk. Global atomics: one per
// (block, bin) = 153K total, 391 per address (vs 4100/address before).
// ---------------------------------------------------------------------------
__launch_bounds__(256)
__global__ void split_kernel(const int* __restrict__ src,
                             const int* __restrict__ dst,
                             int* __restrict__ bcnt,
                             uint_t* __restrict__ bpack) {
    __shared__ uint_t   ebuf[BLK_E];   // 16 KB packed records
    __shared__ ushort_t bbuf[BLK_E];   //  8 KB bucket ids
    __shared__ int      hist[NB];      // counts, then cursors

    const int t  = threadIdx.x;
    const int e0 = blockIdx.x * BLK_E;
    const int n  = min(BLK_E, N_EDGES - e0);

    for (int i = t; i < NB; i += 256) hist[i] = 0;
    __syncthreads();

    for (int i = t; i < n; i += 256) {
        const int d = dst[e0 + i];
        const int s = src[e0 + i];
        const int b = d >> 8;
        ebuf[i] = ((uint_t)s << 8) | (uint_t)(d & 255);
        bbuf[i] = (ushort_t)b;
        atomicAdd(&hist[b], 1);
    }
    __syncthreads();

    // bulk reserve: hist[b] becomes this block's cursor base in bucket b
    for (int i = t; i < NB; i += 256) {
        const int c = hist[i];
        hist[i] = c ? atomicAdd(&bcnt[i], c) : 0;
    }
    __syncthreads();

    for (int i = t; i < n; i += 256) {
        const int b = bbuf[i];
        const int p = atomicAdd(&hist[b], 1);
        if (p < CAP)
            bpack[(size_t)b * CAP + p] = ebuf[i];
    }
}

// ---------------------------------------------------------------------------
// bucket_scan: exclusive scan of 391 bucket counts (one block).
// ---------------------------------------------------------------------------
__global__ void bucket_scan_kernel(const int* __restrict__ bcnt,
                                   int* __restrict__ bbase,
                                   int* __restrict__ offsets) {
    __shared__ int lds[512];
    const int t = threadIdx.x;
    const int v = (t < NB) ? min(bcnt[t], CAP) : 0;
    lds[t] = v;
    __syncthreads();
    int acc = v;
#pragma unroll
    for (int off = 1; off < 512; off <<= 1) {
        const int add = (t >= off) ? lds[t - off] : 0;
        __syncthreads();
        acc += add;
        lds[t] = acc;
        __syncthreads();
    }
    if (t < NB) bbase[t] = acc - v;
    if (t == 511) offsets[N_NODES] = acc;   // total placed edges
}

// ---------------------------------------------------------------------------
// build: one block per bucket. LDS count -> LDS scan -> per-node offsets ->
// place esrc via LDS cursors. Each bucket's esrc window written by ONE block.
// ---------------------------------------------------------------------------
__launch_bounds__(256)
__global__ void build_kernel(const int* __restrict__ bcnt,
                             const int* __restrict__ bbase,
                             const uint_t* __restrict__ bpack,
                             int* __restrict__ offsets,
                             int* __restrict__ esrc) {
    __shared__ uint_t ebuf[CAP];   // 18.4 KB
    __shared__ int cnt[NPB];
    __shared__ int cur[NPB];

    const int b = blockIdx.x;
    const int t = threadIdx.x;
    const int n = min(bcnt[b], CAP);
    const int base = bbase[b];

    cnt[t] = 0;
    __syncthreads();

    for (int i = t; i < n; i += 256) {
        const uint_t v = bpack[(size_t)b * CAP + i];
        ebuf[i] = v;
        atomicAdd(&cnt[v & 255u], 1);
    }
    __syncthreads();

    const int v = cnt[t];
    int acc = v;
    cur[t] = acc;
    __syncthreads();
#pragma unroll
    for (int off = 1; off < 256; off <<= 1) {
        const int add = (t >= off) ? cur[t - off] : 0;
        __syncthreads();
        acc += add;
        cur[t] = acc;
        __syncthreads();
    }
    const int excl = acc - v;

    const int node = b * NPB + t;
    if (node < N_NODES) offsets[node] = base + excl;
    cur[t] = base + excl;
    __syncthreads();

    for (int i = t; i < n; i += 256) {
        const uint_t e = ebuf[i];
        const int p = atomicAdd(&cur[e & 255u], 1);
        esrc[p] = (int)(e >> 8);
    }
}

// ---------------------------------------------------------------------------
// Gather-sum: one wave per dst node, lane = column (bf16 hn). Fused post-scale.
// ---------------------------------------------------------------------------
__global__ void gather_kernel(const ushort_t* __restrict__ hn,
                              const int* __restrict__ offsets,
                              const int* __restrict__ esrc,
                              const float* __restrict__ norm,
                              float* __restrict__ out) {
    const int node = blockIdx.x * (blockDim.x >> 6) + (threadIdx.x >> 6);
    const int lane = threadIdx.x & 63;
    if (node >= N_NODES) return;

    const int beg = offsets[node];
    const int end = offsets[node + 1];

    float acc = 0.f;
    int i = beg;
    for (; i + 3 < end; i += 4) {
        const int s0 = esrc[i], s1 = esrc[i + 1], s2 = esrc[i + 2], s3 = esrc[i + 3];
        const ushort_t a = hn[(size_t)s0 * F + lane];
        const ushort_t b = hn[(size_t)s1 * F + lane];
        const ushort_t c = hn[(size_t)s2 * F + lane];
        const ushort_t d = hn[(size_t)s3 * F + lane];
        acc += bf2f(a) + bf2f(b) + bf2f(c) + bf2f(d);
    }
    for (; i < end; ++i)
        acc += bf2f(hn[(size_t)esrc[i] * F + lane]);

    out[(size_t)node * F + lane] = acc * norm[node];
}

extern "C" void kernel_launch(void* const* d_in, const int* in_sizes, int n_in,
                              void* d_out, int out_size, void* d_ws, size_t ws_size,
                              hipStream_t stream) {
    const float* h    = (const float*)d_in[0];
    const float* w    = (const float*)d_in[1];
    const float* norm = (const float*)d_in[2];
    const int*   src  = (const int*)d_in[3];
    const int*   dst  = (const int*)d_in[4];
    float* out = (float*)d_out;

    // Workspace layout (256-aligned chunks), total ~26.8 MB:
    char* ws = (char*)d_ws;
    ushort_t* hn   = (ushort_t*)ws;                      // 12,800,000 B
    uint_t* bpack  = (uint_t*)(ws + 12800000);           //  7,206,912 B (NB*CAP*4)
    int* bcnt      = (int*)(ws + 20006912);              //      2,048 B
    int* bbase     = (int*)(ws + 20008960);              //      2,048 B
    int* offsets   = (int*)(ws + 20011008);              //    400,384 B
    int* esrc      = (int*)(ws + 20411392);              //  6,400,000 B

    hipMemsetAsync(bcnt, 0, NB * sizeof(int), stream);

    gemm_norm_kernel<<<2048, 256, 0, stream>>>(h, w, norm, hn);

    split_kernel<<<NSPLIT, 256, 0, stream>>>(src, dst, bcnt, bpack);
    bucket_scan_kernel<<<1, 512, 0, stream>>>(bcnt, bbase, offsets);
    build_kernel<<<NB, 256, 0, stream>>>(bcnt, bbase, bpack, offsets, esrc);

    gather_kernel<<<(N_NODES + 3) / 4, 256, 0, stream>>>(hn, offsets, esrc, norm, out);
}

// Round 6
// 140.724 us; speedup vs baseline: 4.9557x; 1.1219x over previous
//
#include <hip/hip_runtime.h>

#define N_NODES 100000
#define N_EDGES 1600000
#define F 64
#define NPB 256                              // nodes per bucket (dst>>8)
#define NB ((N_NODES + NPB - 1) / NPB)       // 391 buckets
#define CAP 4608                             // bucket capacity (mean 4096, +8 sigma)
#define BLK_E 4096                           // edges per split block
#define NSPLIT ((N_EDGES + BLK_E - 1) / BLK_E)   // 391
#define GEMM_BLOCKS 2048
#define SMEM_BYTES (BLK_E * 4 + BLK_E * 2 + 1600)   // ebuf + bbuf + hist (26176 B)

typedef unsigned short ushort_t;
typedef unsigned int uint_t;

// round-to-nearest-even float -> bf16 bits
__device__ __forceinline__ ushort_t f2bf(float x) {
    uint_t u = __float_as_uint(x);
    u += 0x7FFFu + ((u >> 16) & 1u);
    return (ushort_t)(u >> 16);
}

// ---------------------------------------------------------------------------
// Fused kernel: blocks [0, NSPLIT) do the edge bucket-split; blocks
// [NSPLIT, NSPLIT+GEMM_BLOCKS) do hn = bf16((h @ W) * norm). Independent
// work overlapped in one launch; LDS shared via a byte union.
// ---------------------------------------------------------------------------
__launch_bounds__(256)
__global__ void gemm_split_kernel(const float* __restrict__ h,
                                  const float* __restrict__ w,
                                  const float* __restrict__ norm,
                                  ushort_t* __restrict__ hn,
                                  const int* __restrict__ src,
                                  const int* __restrict__ dst,
                                  int* __restrict__ bcnt,
                                  uint_t* __restrict__ bpack) {
    __shared__ __align__(16) char smem[SMEM_BYTES];
    const int t = threadIdx.x;

    if (blockIdx.x < NSPLIT) {
        // ---- split role: LDS histogram + bulk reserve + LDS-cursor place ----
        uint_t*   ebuf = (uint_t*)smem;                       // 16 KB
        ushort_t* bbuf = (ushort_t*)(smem + BLK_E * 4);       //  8 KB
        int*      hist = (int*)(smem + BLK_E * 4 + BLK_E * 2);

        const int e0 = blockIdx.x * BLK_E;
        const int n  = min(BLK_E, N_EDGES - e0);

        for (int i = t; i < NB; i += 256) hist[i] = 0;
        __syncthreads();

        for (int i = t; i < n; i += 256) {
            const int d = dst[e0 + i];
            const int s = src[e0 + i];
            const int b = d >> 8;
            ebuf[i] = ((uint_t)s << 8) | (uint_t)(d & 255);
            bbuf[i] = (ushort_t)b;
            atomicAdd(&hist[b], 1);
        }
        __syncthreads();

        for (int i = t; i < NB; i += 256) {
            const int c = hist[i];
            hist[i] = c ? atomicAdd(&bcnt[i], c) : 0;
        }
        __syncthreads();

        for (int i = t; i < n; i += 256) {
            const int b = bbuf[i];
            const int p = atomicAdd(&hist[b], 1);
            if (p < CAP)
                bpack[(size_t)b * CAP + p] = ebuf[i];
        }
    } else {
        // ---- gemm role ----
        float (*w_lds)[F] = (float (*)[F])smem;               // 16 KB
        float (*h_lds)[F] = (float (*)[F])(smem + F * F * 4); //  1 KB

        const int gb = blockIdx.x - NSPLIT;
        for (int i = t; i < F * F; i += 256)
            ((float*)smem)[i] = w[i];
        __syncthreads();

        const int rl = t >> 6;
        const int c  = t & 63;

        for (int r0 = gb * 4; r0 < N_NODES; r0 += GEMM_BLOCKS * 4) {
            const int r = r0 + rl;
            h_lds[rl][c] = (r < N_NODES) ? h[(size_t)r * F + c] : 0.f;
            __syncthreads();
            if (r < N_NODES) {
                float acc = 0.f;
#pragma unroll
                for (int k = 0; k < F; ++k)
                    acc += h_lds[rl][k] * w_lds[k][c];
                hn[(size_t)r * F + c] = f2bf(acc * norm[r]);
            }
            __syncthreads();
        }
    }
}

// ---------------------------------------------------------------------------
// build: one block per bucket. Inline scan of bucket counts (391 values,
// L2-hot) -> bucket base; then LDS count -> LDS scan -> per-node offsets ->
// place esrc via LDS cursors. Each bucket's esrc window written by ONE block.
// ---------------------------------------------------------------------------
__launch_bounds__(256)
__global__ void build_kernel(const int* __restrict__ bcnt,
                             const uint_t* __restrict__ bpack,
                             int* __restrict__ offsets,
                             int* __restrict__ esrc) {
    __shared__ uint_t ebuf[CAP];   // 18.4 KB
    __shared__ int cnt[NPB];
    __shared__ int cur[NPB];
    __shared__ int sc[256];
    __shared__ int pair0[256];

    const int b = blockIdx.x;
    const int t = threadIdx.x;

    // ---- inline exclusive scan over min(bcnt[j],CAP), pair-per-thread ----
    const int j0 = 2 * t, j1 = 2 * t + 1;
    const int v0 = (j0 < NB) ? min(bcnt[j0], CAP) : 0;
    const int v1 = (j1 < NB) ? min(bcnt[j1], CAP) : 0;
    const int s  = v0 + v1;
    sc[t] = s;
    pair0[t] = v0;
    __syncthreads();
    int acc = s;
#pragma unroll
    for (int off = 1; off < 256; off <<= 1) {
        const int add = (t >= off) ? sc[t - off] : 0;
        __syncthreads();
        acc += add;
        sc[t] = acc;
        __syncthreads();
    }
    // sc[p] = inclusive sum of pairs 0..p
    const int pair = b >> 1;
    const int base = ((pair > 0) ? sc[pair - 1] : 0) + ((b & 1) ? pair0[pair] : 0);
    if (b == 0 && t == 0) offsets[N_NODES] = sc[255];

    const int n = min(bcnt[b], CAP);

    cnt[t] = 0;
    __syncthreads();

    for (int i = t; i < n; i += 256) {
        const uint_t v = bpack[(size_t)b * CAP + i];
        ebuf[i] = v;
        atomicAdd(&cnt[v & 255u], 1);
    }
    __syncthreads();

    const int v = cnt[t];
    int acc2 = v;
    cur[t] = acc2;
    __syncthreads();
#pragma unroll
    for (int off = 1; off < 256; off <<= 1) {
        const int add = (t >= off) ? cur[t - off] : 0;
        __syncthreads();
        acc2 += add;
        cur[t] = acc2;
        __syncthreads();
    }
    const int excl = acc2 - v;

    const int node = b * NPB + t;
    if (node < N_NODES) offsets[node] = base + excl;
    cur[t] = base + excl;
    __syncthreads();

    for (int i = t; i < n; i += 256) {
        const uint_t e = ebuf[i];
        const int p = atomicAdd(&cur[e & 255u], 1);
        esrc[p] = (int)(e >> 8);
    }
}

// ---------------------------------------------------------------------------
// Gather-sum: one wave per dst node. lane = (edge-slot p, column-pair c):
// each lane loads a uint (2 bf16 cols), so one wave-load consumes 2 edges'
// rows. Cross-half combine via shfl_xor(32); float2 store by 32 lanes.
// ---------------------------------------------------------------------------
__global__ void gather_kernel(const ushort_t* __restrict__ hn,
                              const int* __restrict__ offsets,
                              const int* __restrict__ esrc,
                              const float* __restrict__ norm,
                              float* __restrict__ out) {
    const int node = blockIdx.x * (blockDim.x >> 6) + (threadIdx.x >> 6);
    const int lane = threadIdx.x & 63;
    if (node >= N_NODES) return;

    const int c = lane & 31;   // column pair: cols 2c, 2c+1
    const int p = lane >> 5;   // edge slot within a 2-edge group

    const int beg = offsets[node];
    const int end = offsets[node + 1];

    float a0 = 0.f, a1 = 0.f;
    int i = beg;
    for (; i + 3 < end; i += 4) {
        const int s0 = esrc[i + p * 2];
        const int s1 = esrc[i + p * 2 + 1];
        const uint_t v0 = *(const uint_t*)(hn + (size_t)s0 * F + 2 * c);
        const uint_t v1 = *(const uint_t*)(hn + (size_t)s1 * F + 2 * c);
        a0 += __uint_as_float(v0 << 16) + __uint_as_float(v1 << 16);
        a1 += __uint_as_float(v0 & 0xFFFF0000u) + __uint_as_float(v1 & 0xFFFF0000u);
    }
    for (; i < end; i += 2) {
        const int e = i + p;
        if (e < end) {
            const int s = esrc[e];
            const uint_t v = *(const uint_t*)(hn + (size_t)s * F + 2 * c);
            a0 += __uint_as_float(v << 16);
            a1 += __uint_as_float(v & 0xFFFF0000u);
        }
    }

    a0 += __shfl_xor(a0, 32);
    a1 += __shfl_xor(a1, 32);

    if (p == 0) {
        const float nv = norm[node];
        float2 r;
        r.x = a0 * nv;
        r.y = a1 * nv;
        *(float2*)(out + (size_t)node * F + 2 * c) = r;
    }
}

extern "C" void kernel_launch(void* const* d_in, const int* in_sizes, int n_in,
                              void* d_out, int out_size, void* d_ws, size_t ws_size,
                              hipStream_t stream) {
    const float* h    = (const float*)d_in[0];
    const float* w    = (const float*)d_in[1];
    const float* norm = (const float*)d_in[2];
    const int*   src  = (const int*)d_in[3];
    const int*   dst  = (const int*)d_in[4];
    float* out = (float*)d_out;

    // Workspace layout (256-aligned chunks), total ~26.8 MB:
    char* ws = (char*)d_ws;
    ushort_t* hn   = (ushort_t*)ws;                      // 12,800,000 B
    uint_t* bpack  = (uint_t*)(ws + 12800000);           //  7,206,912 B (NB*CAP*4)
    int* bcnt      = (int*)(ws + 20006912);              //      2,048 B
    int* offsets   = (int*)(ws + 20008960);              //    400,384 B
    int* esrc      = (int*)(ws + 20409344);              //  6,400,000 B

    hipMemsetAsync(bcnt, 0, NB * sizeof(int), stream);

    gemm_split_kernel<<<NSPLIT + GEMM_BLOCKS, 256, 0, stream>>>(
        h, w, norm, hn, src, dst, bcnt, bpack);

    build_kernel<<<NB, 256, 0, stream>>>(bcnt, bpack, offsets, esrc);

    gather_kernel<<<(N_NODES + 3) / 4, 256, 0, stream>>>(hn, offsets, esrc, norm, out);
}

// Round 7
// 112.668 us; speedup vs baseline: 6.1898x; 1.2490x over previous
//
#include <hip/hip_runtime.h>

#define N_NODES 100000
#define N_EDGES 1600000
#define F 64
#define NPB 256                              // nodes per bucket (dst>>8)
#define NB ((N_NODES + NPB - 1) / NPB)       // 391 buckets
#define CAP 4608                             // bucket capacity (mean 4096, +8 sigma)
#define BLK_E 4096                           // edges per split block
#define NSPLIT ((N_EDGES + BLK_E - 1) / BLK_E)   // 391
#define GEMM_ROWS 64                         // rows per gemm block
#define NGEMM ((N_NODES + GEMM_ROWS - 1) / GEMM_ROWS)  // 1563
#define SMEM_BYTES (BLK_E * 4 + BLK_E * 2 + 1600)      // split role LDS (26176 B)

typedef unsigned short ushort_t;
typedef unsigned int uint_t;
using bf16x8 = __attribute__((ext_vector_type(8))) short;
using f32x4  = __attribute__((ext_vector_type(4))) float;

// round-to-nearest-even float -> bf16 bits
__device__ __forceinline__ ushort_t f2bf(float x) {
    uint_t u = __float_as_uint(x);
    u += 0x7FFFu + ((u >> 16) & 1u);
    return (ushort_t)(u >> 16);
}
__device__ __forceinline__ float bflo(uint_t v) {   // low bf16 of a uint
    return __uint_as_float(v << 16);
}
__device__ __forceinline__ float bfhi(uint_t v) {   // high bf16 of a uint
    return __uint_as_float(v & 0xFFFF0000u);
}

// ---------------------------------------------------------------------------
// Fused kernel: blocks [0, NSPLIT) do the edge bucket-split (LDS histogram +
// bulk reserve); blocks [NSPLIT, NSPLIT+NGEMM) do hn = bf16((h@W)*norm) via
// MFMA (no LDS in the gemm role). Independent work overlapped in one launch.
//
// MFMA 16x16x32 bf16 layouts (m89-verified D; standard A/B):
//   A: m = lane&15,  k = (lane>>4)*8 + j   (j = 0..7)
//   B: n = lane&15,  k = (lane>>4)*8 + j
//   D: n = lane&15,  m = (lane>>4)*4 + reg
// ---------------------------------------------------------------------------
__launch_bounds__(256)
__global__ void gemm_split_kernel(const float* __restrict__ h,
                                  const float* __restrict__ w,
                                  const float* __restrict__ norm,
                                  ushort_t* __restrict__ hn,
                                  const int* __restrict__ src,
                                  const int* __restrict__ dst,
                                  int* __restrict__ bcnt,
                                  uint_t* __restrict__ bpack) {
    __shared__ __align__(16) char smem[SMEM_BYTES];
    const int t = threadIdx.x;

    if (blockIdx.x < NSPLIT) {
        // ---- split role: LDS histogram + bulk reserve + LDS-cursor place ----
        uint_t*   ebuf = (uint_t*)smem;                       // 16 KB
        ushort_t* bbuf = (ushort_t*)(smem + BLK_E * 4);       //  8 KB
        int*      hist = (int*)(smem + BLK_E * 4 + BLK_E * 2);

        const int e0 = blockIdx.x * BLK_E;
        const int n  = min(BLK_E, N_EDGES - e0);

        for (int i = t; i < NB; i += 256) hist[i] = 0;
        __syncthreads();

        for (int i = t; i < n; i += 256) {
            const int d = dst[e0 + i];
            const int s = src[e0 + i];
            const int b = d >> 8;
            ebuf[i] = ((uint_t)s << 8) | (uint_t)(d & 255);
            bbuf[i] = (ushort_t)b;
            atomicAdd(&hist[b], 1);
        }
        __syncthreads();

        for (int i = t; i < NB; i += 256) {
            const int c = hist[i];
            hist[i] = c ? atomicAdd(&bcnt[i], c) : 0;
        }
        __syncthreads();

        for (int i = t; i < n; i += 256) {
            const int b = bbuf[i];
            const int p = atomicAdd(&hist[b], 1);
            if (p < CAP)
                bpack[(size_t)b * CAP + p] = ebuf[i];
        }
    } else {
        // ---- gemm role: MFMA, 4 waves x 16 cols, 4 row-tiles per wave ----
        const int gb  = blockIdx.x - NSPLIT;
        const int wv  = t >> 6;        // wave 0..3 -> cols 16*wv..16*wv+15
        const int l   = t & 63;
        const int lr  = l & 15;        // A-row / B-col / D-col within tile
        const int lk  = l >> 4;        // k-group (8 elems each)
        const int col = wv * 16 + lr;
        const int r0  = gb * GEMM_ROWS;

        // B fragments for k0=0 and k0=32 (W is 16 KB, L2-hot across blocks)
        bf16x8 b0, b1;
#pragma unroll
        for (int j = 0; j < 8; ++j) {
            b0[j] = (short)f2bf(w[(lk * 8 + j) * F + col]);
            b1[j] = (short)f2bf(w[(32 + lk * 8 + j) * F + col]);
        }

#pragma unroll
        for (int tt = 0; tt < 4; ++tt) {
            const int r  = r0 + tt * 16 + lr;
            const int rl = min(r, N_NODES - 1);
            const float4 ha0 = *(const float4*)(h + (size_t)rl * F + lk * 8);
            const float4 ha1 = *(const float4*)(h + (size_t)rl * F + lk * 8 + 4);
            const float4 hb0 = *(const float4*)(h + (size_t)rl * F + 32 + lk * 8);
            const float4 hb1 = *(const float4*)(h + (size_t)rl * F + 32 + lk * 8 + 4);
            bf16x8 a0, a1;
            a0[0] = (short)f2bf(ha0.x); a0[1] = (short)f2bf(ha0.y);
            a0[2] = (short)f2bf(ha0.z); a0[3] = (short)f2bf(ha0.w);
            a0[4] = (short)f2bf(ha1.x); a0[5] = (short)f2bf(ha1.y);
            a0[6] = (short)f2bf(ha1.z); a0[7] = (short)f2bf(ha1.w);
            a1[0] = (short)f2bf(hb0.x); a1[1] = (short)f2bf(hb0.y);
            a1[2] = (short)f2bf(hb0.z); a1[3] = (short)f2bf(hb0.w);
            a1[4] = (short)f2bf(hb1.x); a1[5] = (short)f2bf(hb1.y);
            a1[6] = (short)f2bf(hb1.z); a1[7] = (short)f2bf(hb1.w);

            f32x4 acc = {0.f, 0.f, 0.f, 0.f};
            acc = __builtin_amdgcn_mfma_f32_16x16x32_bf16(a0, b0, acc, 0, 0, 0);
            acc = __builtin_amdgcn_mfma_f32_16x16x32_bf16(a1, b1, acc, 0, 0, 0);

#pragma unroll
            for (int i2 = 0; i2 < 4; ++i2) {
                const int m = r0 + tt * 16 + lk * 4 + i2;
                if (m < N_NODES)
                    hn[(size_t)m * F + col] = f2bf(acc[i2] * norm[m]);
            }
        }
    }
}

// ---------------------------------------------------------------------------
// build: one block per bucket. Inline scan of bucket counts (391 values,
// L2-hot) -> bucket base; then LDS count -> LDS scan -> per-node offsets ->
// place esrc via LDS cursors. Each bucket's esrc window written by ONE block.
// ---------------------------------------------------------------------------
__launch_bounds__(256)
__global__ void build_kernel(const int* __restrict__ bcnt,
                             const uint_t* __restrict__ bpack,
                             int* __restrict__ offsets,
                             int* __restrict__ esrc) {
    __shared__ uint_t ebuf[CAP];   // 18.4 KB
    __shared__ int cnt[NPB];
    __shared__ int cur[NPB];
    __shared__ int sc[256];
    __shared__ int pair0[256];

    const int b = blockIdx.x;
    const int t = threadIdx.x;

    // ---- inline exclusive scan over min(bcnt[j],CAP), pair-per-thread ----
    const int j0 = 2 * t, j1 = 2 * t + 1;
    const int v0 = (j0 < NB) ? min(bcnt[j0], CAP) : 0;
    const int v1 = (j1 < NB) ? min(bcnt[j1], CAP) : 0;
    const int s  = v0 + v1;
    sc[t] = s;
    pair0[t] = v0;
    __syncthreads();
    int acc = s;
#pragma unroll
    for (int off = 1; off < 256; off <<= 1) {
        const int add = (t >= off) ? sc[t - off] : 0;
        __syncthreads();
        acc += add;
        sc[t] = acc;
        __syncthreads();
    }
    const int pair = b >> 1;
    const int base = ((pair > 0) ? sc[pair - 1] : 0) + ((b & 1) ? pair0[pair] : 0);
    if (b == 0 && t == 0) offsets[N_NODES] = sc[255];

    const int n = min(bcnt[b], CAP);

    cnt[t] = 0;
    __syncthreads();

    for (int i = t; i < n; i += 256) {
        const uint_t v = bpack[(size_t)b * CAP + i];
        ebuf[i] = v;
        atomicAdd(&cnt[v & 255u], 1);
    }
    __syncthreads();

    const int v = cnt[t];
    int acc2 = v;
    cur[t] = acc2;
    __syncthreads();
#pragma unroll
    for (int off = 1; off < 256; off <<= 1) {
        const int add = (t >= off) ? cur[t - off] : 0;
        __syncthreads();
        acc2 += add;
        cur[t] = acc2;
        __syncthreads();
    }
    const int excl = acc2 - v;

    const int node = b * NPB + t;
    if (node < N_NODES) offsets[node] = base + excl;
    cur[t] = base + excl;
    __syncthreads();

    for (int i = t; i < n; i += 256) {
        const uint_t e = ebuf[i];
        const int p = atomicAdd(&cur[e & 255u], 1);
        esrc[p] = (int)(e >> 8);
    }
}

// ---------------------------------------------------------------------------
// Gather-sum: one wave per dst node. lane = (slot s in 0..3, colgroup c in
// 0..15). Each lane loads uint2 (4 bf16 cols) -> 4 edges serviced per load
// round, unrolled x2 (8 edges, 2 loads in flight per lane). Slot reduce via
// shfl_xor(16,32); 16 lanes store float4 (256 B coalesced row).
// ---------------------------------------------------------------------------
__global__ void gather_kernel(const ushort_t* __restrict__ hn,
                              const int* __restrict__ offsets,
                              const int* __restrict__ esrc,
                              const float* __restrict__ norm,
                              float* __restrict__ out) {
    const int node = blockIdx.x * (blockDim.x >> 6) + (threadIdx.x >> 6);
    const int lane = threadIdx.x & 63;
    if (node >= N_NODES) return;

    const int s = lane >> 4;   // edge slot
    const int c = lane & 15;   // col group: cols 4c..4c+3

    const int beg = offsets[node];
    const int end = offsets[node + 1];

    float a0 = 0.f, a1 = 0.f, a2 = 0.f, a3 = 0.f;
    int i = beg;
    for (; i + 7 < end; i += 8) {
        const int sA = esrc[i + s];
        const int sB = esrc[i + 4 + s];
        const uint2 vA = *(const uint2*)(hn + (size_t)sA * F + 4 * c);
        const uint2 vB = *(const uint2*)(hn + (size_t)sB * F + 4 * c);
        a0 += bflo(vA.x) + bflo(vB.x);
        a1 += bfhi(vA.x) + bfhi(vB.x);
        a2 += bflo(vA.y) + bflo(vB.y);
        a3 += bfhi(vA.y) + bfhi(vB.y);
    }
    for (; i < end; i += 4) {
        const int e = i + s;
        if (e < end) {
            const int sv = esrc[e];
            const uint2 v = *(const uint2*)(hn + (size_t)sv * F + 4 * c);
            a0 += bflo(v.x);
            a1 += bfhi(v.x);
            a2 += bflo(v.y);
            a3 += bfhi(v.y);
        }
    }

    a0 += __shfl_xor(a0, 16); a0 += __shfl_xor(a0, 32);
    a1 += __shfl_xor(a1, 16); a1 += __shfl_xor(a1, 32);
    a2 += __shfl_xor(a2, 16); a2 += __shfl_xor(a2, 32);
    a3 += __shfl_xor(a3, 16); a3 += __shfl_xor(a3, 32);

    if (s == 0) {
        const float nv = norm[node];
        float4 r;
        r.x = a0 * nv; r.y = a1 * nv; r.z = a2 * nv; r.w = a3 * nv;
        *(float4*)(out + (size_t)node * F + 4 * c) = r;
    }
}

extern "C" void kernel_launch(void* const* d_in, const int* in_sizes, int n_in,
                              void* d_out, int out_size, void* d_ws, size_t ws_size,
                              hipStream_t stream) {
    const float* h    = (const float*)d_in[0];
    const float* w    = (const float*)d_in[1];
    const float* norm = (const float*)d_in[2];
    const int*   src  = (const int*)d_in[3];
    const int*   dst  = (const int*)d_in[4];
    float* out = (float*)d_out;

    // Workspace layout (256-aligned chunks), total ~26.8 MB:
    char* ws = (char*)d_ws;
    ushort_t* hn   = (ushort_t*)ws;                      // 12,800,000 B
    uint_t* bpack  = (uint_t*)(ws + 12800000);           //  7,206,912 B (NB*CAP*4)
    int* bcnt      = (int*)(ws + 20006912);              //      2,048 B
    int* offsets   = (int*)(ws + 20008960);              //    400,384 B
    int* esrc      = (int*)(ws + 20409344);              //  6,400,000 B

    hipMemsetAsync(bcnt, 0, NB * sizeof(int), stream);

    gemm_split_kernel<<<NSPLIT + NGEMM, 256, 0, stream>>>(
        h, w, norm, hn, src, dst, bcnt, bpack);

    build_kernel<<<NB, 256, 0, stream>>>(bcnt, bpack, offsets, esrc);

    gather_kernel<<<(N_NODES + 3) / 4, 256, 0, stream>>>(hn, offsets, esrc, norm, out);
}

// Round 8
// 84.174 us; speedup vs baseline: 8.2851x; 1.3385x over previous
//
#include <hip/hip_runtime.h>

#define N_NODES 100000
#define N_EDGES 1600000
#define F 64
#define NPB 128                              // nodes per bucket (dst>>7)
#define NB ((N_NODES + NPB - 1) / NPB)       // 782 buckets
#define CAP 2432                             // bucket capacity (mean 2048, +8.5 sigma)
#define BLK_E 4096                           // edges per split block
#define NSPLIT ((N_EDGES + BLK_E - 1) / BLK_E)   // 391
#define GEMM_ROWS 64                         // rows per gemm block
#define NGEMM ((N_NODES + GEMM_ROWS - 1) / GEMM_ROWS)  // 1563
#define SMEM_BYTES (BLK_E * 4 + BLK_E * 2 + NB * 4)    // split role LDS (27704 B)

typedef unsigned short ushort_t;
typedef unsigned int uint_t;
using bf16x8 = __attribute__((ext_vector_type(8))) short;
using f32x4  = __attribute__((ext_vector_type(4))) float;

// round-to-nearest-even float -> bf16 bits
__device__ __forceinline__ ushort_t f2bf(float x) {
    uint_t u = __float_as_uint(x);
    u += 0x7FFFu + ((u >> 16) & 1u);
    return (ushort_t)(u >> 16);
}
__device__ __forceinline__ float bflo(uint_t v) {   // low bf16 of a uint
    return __uint_as_float(v << 16);
}
__device__ __forceinline__ float bfhi(uint_t v) {   // high bf16 of a uint
    return __uint_as_float(v & 0xFFFF0000u);
}

// ---------------------------------------------------------------------------
// Fused kernel: blocks [0, NSPLIT) do the edge bucket-split (LDS histogram +
// bulk reserve); blocks [NSPLIT, NSPLIT+NGEMM) do hn = bf16((h@W)*norm) via
// MFMA. Independent work overlapped in one launch.
//
// Packed record: (src << 7) | (dst & 127)  -- 17+7 = 24 bits.
//
// MFMA 16x16x32 bf16 layouts (m89-verified D; standard A/B):
//   A: m = lane&15,  k = (lane>>4)*8 + j   (j = 0..7)
//   B: n = lane&15,  k = (lane>>4)*8 + j
//   D: n = lane&15,  m = (lane>>4)*4 + reg
// ---------------------------------------------------------------------------
__launch_bounds__(256)
__global__ void gemm_split_kernel(const float* __restrict__ h,
                                  const float* __restrict__ w,
                                  const float* __restrict__ norm,
                                  ushort_t* __restrict__ hn,
                                  const int* __restrict__ src,
                                  const int* __restrict__ dst,
                                  int* __restrict__ bcnt,
                                  uint_t* __restrict__ bpack) {
    __shared__ __align__(16) char smem[SMEM_BYTES];
    const int t = threadIdx.x;

    if (blockIdx.x < NSPLIT) {
        // ---- split role: LDS histogram + bulk reserve + LDS-cursor place ----
        uint_t*   ebuf = (uint_t*)smem;                       // 16 KB
        ushort_t* bbuf = (ushort_t*)(smem + BLK_E * 4);       //  8 KB
        int*      hist = (int*)(smem + BLK_E * 4 + BLK_E * 2);

        const int e0 = blockIdx.x * BLK_E;
        const int n  = min(BLK_E, N_EDGES - e0);

        for (int i = t; i < NB; i += 256) hist[i] = 0;
        __syncthreads();

        for (int i = t; i < n; i += 256) {
            const int d = dst[e0 + i];
            const int s = src[e0 + i];
            const int b = d >> 7;
            ebuf[i] = ((uint_t)s << 7) | (uint_t)(d & 127);
            bbuf[i] = (ushort_t)b;
            atomicAdd(&hist[b], 1);
        }
        __syncthreads();

        for (int i = t; i < NB; i += 256) {
            const int c = hist[i];
            hist[i] = c ? atomicAdd(&bcnt[i], c) : 0;
        }
        __syncthreads();

        for (int i = t; i < n; i += 256) {
            const int b = bbuf[i];
            const int p = atomicAdd(&hist[b], 1);
            if (p < CAP)
                bpack[(size_t)b * CAP + p] = ebuf[i];
        }
    } else {
        // ---- gemm role: MFMA, 4 waves x 16 cols, 4 row-tiles per wave ----
        const int gb  = blockIdx.x - NSPLIT;
        const int wv  = t >> 6;        // wave 0..3 -> cols 16*wv..16*wv+15
        const int l   = t & 63;
        const int lr  = l & 15;
        const int lk  = l >> 4;
        const int col = wv * 16 + lr;
        const int r0  = gb * GEMM_ROWS;

        bf16x8 b0, b1;
#pragma unroll
        for (int j = 0; j < 8; ++j) {
            b0[j] = (short)f2bf(w[(lk * 8 + j) * F + col]);
            b1[j] = (short)f2bf(w[(32 + lk * 8 + j) * F + col]);
        }

#pragma unroll
        for (int tt = 0; tt < 4; ++tt) {
            const int r  = r0 + tt * 16 + lr;
            const int rl = min(r, N_NODES - 1);
            const float4 ha0 = *(const float4*)(h + (size_t)rl * F + lk * 8);
            const float4 ha1 = *(const float4*)(h + (size_t)rl * F + lk * 8 + 4);
            const float4 hb0 = *(const float4*)(h + (size_t)rl * F + 32 + lk * 8);
            const float4 hb1 = *(const float4*)(h + (size_t)rl * F + 32 + lk * 8 + 4);
            bf16x8 a0, a1;
            a0[0] = (short)f2bf(ha0.x); a0[1] = (short)f2bf(ha0.y);
            a0[2] = (short)f2bf(ha0.z); a0[3] = (short)f2bf(ha0.w);
            a0[4] = (short)f2bf(ha1.x); a0[5] = (short)f2bf(ha1.y);
            a0[6] = (short)f2bf(ha1.z); a0[7] = (short)f2bf(ha1.w);
            a1[0] = (short)f2bf(hb0.x); a1[1] = (short)f2bf(hb0.y);
            a1[2] = (short)f2bf(hb0.z); a1[3] = (short)f2bf(hb0.w);
            a1[4] = (short)f2bf(hb1.x); a1[5] = (short)f2bf(hb1.y);
            a1[6] = (short)f2bf(hb1.z); a1[7] = (short)f2bf(hb1.w);

            f32x4 acc = {0.f, 0.f, 0.f, 0.f};
            acc = __builtin_amdgcn_mfma_f32_16x16x32_bf16(a0, b0, acc, 0, 0, 0);
            acc = __builtin_amdgcn_mfma_f32_16x16x32_bf16(a1, b1, acc, 0, 0, 0);

#pragma unroll
            for (int i2 = 0; i2 < 4; ++i2) {
                const int m = r0 + tt * 16 + lk * 4 + i2;
                if (m < N_NODES)
                    hn[(size_t)m * F + col] = f2bf(acc[i2] * norm[m]);
            }
        }
    }
}

// ---------------------------------------------------------------------------
// Fused build+gather: one block (512 thr) per bucket of 128 dst nodes.
// Stage records in LDS -> LDS count/scan -> bucket-LOCAL edge list in LDS ->
// register-accumulating gather (wave per node), fused post-scale, one store.
// No global esrc/offsets, no inter-bucket scan.
// ---------------------------------------------------------------------------
__launch_bounds__(512)
__global__ void gather_build_kernel(const int* __restrict__ bcnt,
                                    const uint_t* __restrict__ bpack,
                                    const ushort_t* __restrict__ hn,
                                    const float* __restrict__ norm,
                                    float* __restrict__ out) {
    __shared__ uint_t ebuf[CAP];     // 9.7 KB packed records
    __shared__ int    lsrc[CAP];     // 9.7 KB bucket-local edge list (src ids)
    __shared__ int    cnt[NPB];
    __shared__ int    beg[NPB];
    __shared__ int    cur[NPB];
    __shared__ int    sc[NPB];

    const int b = blockIdx.x;
    const int t = threadIdx.x;
    const int n = min(bcnt[b], CAP);

    if (t < NPB) cnt[t] = 0;
    __syncthreads();

    for (int i = t; i < n; i += 512) {
        const uint_t v = bpack[(size_t)b * CAP + i];
        ebuf[i] = v;
        atomicAdd(&cnt[v & 127u], 1);
    }
    __syncthreads();

    // Hillis-Steele inclusive scan over 128 counts (threads t<128 active)
    int acc = (t < NPB) ? cnt[t] : 0;
    if (t < NPB) sc[t] = acc;
    __syncthreads();
#pragma unroll
    for (int off = 1; off < NPB; off <<= 1) {
        int add = 0;
        if (t < NPB && t >= off) add = sc[t - off];
        __syncthreads();
        if (t < NPB) { acc += add; sc[t] = acc; }
        __syncthreads();
    }
    if (t < NPB) {
        const int e = acc - cnt[t];
        beg[t] = e;
        cur[t] = e;
    }
    __syncthreads();

    for (int i = t; i < n; i += 512) {
        const uint_t e = ebuf[i];
        const int p = atomicAdd(&cur[e & 127u], 1);
        lsrc[p] = (int)(e >> 7);
    }
    __syncthreads();

    // gather: wave w handles local nodes w, w+8, ...
    const int wave = t >> 6;
    const int lane = t & 63;
    const int s = lane >> 4;   // edge slot
    const int c = lane & 15;   // col group: cols 4c..4c+3

    for (int ld = wave; ld < NPB; ld += 8) {
        const int node = b * NPB + ld;
        if (node >= N_NODES) break;

        const int bg = beg[ld];
        const int en = bg + cnt[ld];

        float a0 = 0.f, a1 = 0.f, a2 = 0.f, a3 = 0.f;
        int i = bg;
        for (; i + 7 < en; i += 8) {
            const int sA = lsrc[i + s];
            const int sB = lsrc[i + 4 + s];
            const uint2 vA = *(const uint2*)(hn + (size_t)sA * F + 4 * c);
            const uint2 vB = *(const uint2*)(hn + (size_t)sB * F + 4 * c);
            a0 += bflo(vA.x) + bflo(vB.x);
            a1 += bfhi(vA.x) + bfhi(vB.x);
            a2 += bflo(vA.y) + bflo(vB.y);
            a3 += bfhi(vA.y) + bfhi(vB.y);
        }
        for (; i < en; i += 4) {
            const int e = i + s;
            if (e < en) {
                const int sv = lsrc[e];
                const uint2 v = *(const uint2*)(hn + (size_t)sv * F + 4 * c);
                a0 += bflo(v.x);
                a1 += bfhi(v.x);
                a2 += bflo(v.y);
                a3 += bfhi(v.y);
            }
        }

        a0 += __shfl_xor(a0, 16); a0 += __shfl_xor(a0, 32);
        a1 += __shfl_xor(a1, 16); a1 += __shfl_xor(a1, 32);
        a2 += __shfl_xor(a2, 16); a2 += __shfl_xor(a2, 32);
        a3 += __shfl_xor(a3, 16); a3 += __shfl_xor(a3, 32);

        if (s == 0) {
            const float nv = norm[node];
            float4 r;
            r.x = a0 * nv; r.y = a1 * nv; r.z = a2 * nv; r.w = a3 * nv;
            *(float4*)(out + (size_t)node * F + 4 * c) = r;
        }
    }
}

extern "C" void kernel_launch(void* const* d_in, const int* in_sizes, int n_in,
                              void* d_out, int out_size, void* d_ws, size_t ws_size,
                              hipStream_t stream) {
    const float* h    = (const float*)d_in[0];
    const float* w    = (const float*)d_in[1];
    const float* norm = (const float*)d_in[2];
    const int*   src  = (const int*)d_in[3];
    const int*   dst  = (const int*)d_in[4];
    float* out = (float*)d_out;

    // Workspace layout (256-aligned chunks), total ~20.4 MB:
    char* ws = (char*)d_ws;
    ushort_t* hn  = (ushort_t*)ws;                       // 12,800,000 B
    uint_t* bpack = (uint_t*)(ws + 12800000);            //  7,607,296 B (NB*CAP*4)
    int* bcnt     = (int*)(ws + 12800000 + 7607296);     //      3,328 B

    hipMemsetAsync(bcnt, 0, NB * sizeof(int), stream);

    gemm_split_kernel<<<NSPLIT + NGEMM, 256, 0, stream>>>(
        h, w, norm, hn, src, dst, bcnt, bpack);

    gather_build_kernel<<<NB, 512, 0, stream>>>(bcnt, bpack, hn, norm, out);
}